// Round 1
// baseline (197.390 us; speedup 1.0000x reference)
//
#include <hip/hip_runtime.h>

// BiaffineModule: B=4,S=256,H=768,F=32,T=256,WD=64,C=16
// out[b,s,e,c] = sum_u (sum_t s[b,s,t]U[t,c,u]) e[b,e,u]
//              + (s@Ws)[b,s,c] + (e@We)[b,e,c] + (wh@Ww)[s,e,c] + lin_b[c]

#define B_ 4
#define S_ 256
#define H_ 768
#define F_ 32
#define T_ 256
#define WD_ 64
#define C_ 16
#define R_ (B_*S_)    // 1024
#define HF_ (H_+F_)   // 800

// ---------------------------------------------------------------------------
// Kernel 1: SE[r][j] (1024 x 512) = x @ [start_W | end_W] + [sb | eb]
// x[r][k] = k<768 ? final_hidden[r*768+k] : feature_vecs[r*32+k-768]
// ---------------------------------------------------------------------------
__global__ __launch_bounds__(256)
void k_se(const float* __restrict__ fh, const float* __restrict__ fv,
          const float* __restrict__ sW, const float* __restrict__ sb,
          const float* __restrict__ eW, const float* __restrict__ eb,
          float* __restrict__ SE)
{
    __shared__ float As[16][68];
    __shared__ float Bs[16][68];
    const int tid = threadIdx.x;
    const int tx = tid & 15, ty = tid >> 4;
    const int bm = blockIdx.x * 64;   // r tile
    const int bn = blockIdx.y * 64;   // j tile
    float acc[4][4] = {};

    for (int k0 = 0; k0 < HF_; k0 += 16) {
#pragma unroll
        for (int i = 0; i < 4; ++i) {
            int idx = tid + i * 256;
            int ar = idx >> 4, ak = idx & 15;
            int r = bm + ar, k = k0 + ak;
            float v = (k < H_) ? fh[r * H_ + k] : fv[r * F_ + (k - H_)];
            As[ak][ar] = v;
        }
#pragma unroll
        for (int i = 0; i < 4; ++i) {
            int idx = tid + i * 256;
            int bk = idx >> 6, bj = idx & 63;
            int k = k0 + bk, j = bn + bj;
            float v = (j < T_) ? sW[k * T_ + j] : eW[k * T_ + (j - T_)];
            Bs[bk][bj] = v;
        }
        __syncthreads();
#pragma unroll
        for (int kk = 0; kk < 16; ++kk) {
            float4 a4 = *(const float4*)&As[kk][ty * 4];
            float4 b4 = *(const float4*)&Bs[kk][tx * 4];
            float av[4] = {a4.x, a4.y, a4.z, a4.w};
            float bv[4] = {b4.x, b4.y, b4.z, b4.w};
#pragma unroll
            for (int i = 0; i < 4; ++i)
#pragma unroll
                for (int j = 0; j < 4; ++j)
                    acc[i][j] += av[i] * bv[j];
        }
        __syncthreads();
    }

    const int j0 = bn + tx * 4;
    float bias[4];
#pragma unroll
    for (int j = 0; j < 4; ++j) {
        int jj = j0 + j;
        bias[j] = (jj < T_) ? sb[jj] : eb[jj - T_];
    }
#pragma unroll
    for (int i = 0; i < 4; ++i) {
        int r = bm + ty * 4 + i;
        float4 o;
        o.x = acc[i][0] + bias[0];
        o.y = acc[i][1] + bias[1];
        o.z = acc[i][2] + bias[2];
        o.w = acc[i][3] + bias[3];
        *(float4*)&SE[r * 512 + j0] = o;
    }
}

// ---------------------------------------------------------------------------
// Kernel 1b: SCEC[r][0:16] = s_row @ Ws ; SCEC[r][16:32] = e_row @ We
// Ws = lin_W[0:256], We = lin_W[256:512]
// ---------------------------------------------------------------------------
__global__ __launch_bounds__(256)
void k_scec(const float* __restrict__ SE, const float* __restrict__ linW,
            float* __restrict__ SCEC)
{
    __shared__ float SEl[16][512];
    const int tid = threadIdx.x;
    const int r0 = blockIdx.x * 16;
#pragma unroll
    for (int i = 0; i < 8; ++i) {
        int f4 = tid + i * 256;
        int rl = f4 >> 7, t4 = f4 & 127;
        *(float4*)&SEl[rl][t4 * 4] = *(const float4*)&SE[(r0 + rl) * 512 + t4 * 4];
    }
    __syncthreads();
    const int rl = tid >> 4, c = tid & 15;
    float accs = 0.f, acce = 0.f;
#pragma unroll 4
    for (int t = 0; t < 256; ++t) {
        accs += SEl[rl][t]       * linW[t * 16 + c];
        acce += SEl[rl][256 + t] * linW[(256 + t) * 16 + c];
    }
    SCEC[(r0 + rl) * 32 + c]      = accs;
    SCEC[(r0 + rl) * 32 + 16 + c] = acce;
}

// ---------------------------------------------------------------------------
// Kernel 2: WC[se][c] = width_hidden[se][:] @ Ww + lin_b[c]
// Ww = lin_W[512:576]
// ---------------------------------------------------------------------------
__global__ __launch_bounds__(256)
void k_wc(const float* __restrict__ WH, const float* __restrict__ linW,
          const float* __restrict__ linb, float* __restrict__ WC)
{
    __shared__ float Wl[16][64];
    __shared__ float Wwl[64][16];
    const int tid = threadIdx.x;
    const int se0 = blockIdx.x * 16;
    {
        int sel = tid >> 4, w4 = tid & 15;
        *(float4*)&Wl[sel][w4 * 4] = *(const float4*)&WH[(se0 + sel) * 64 + w4 * 4];
    }
    {
        int w = tid >> 2, c4 = tid & 3;
        *(float4*)&Wwl[w][c4 * 4] = *(const float4*)&linW[(512 + w) * 16 + c4 * 4];
    }
    __syncthreads();
    const int sel = tid >> 4, c = tid & 15;
    float acc = linb[c];
#pragma unroll
    for (int w = 0; w < 64; ++w)
        acc += Wl[sel][w] * Wwl[w][c];
    WC[(se0 + sel) * 16 + c] = acc;
}

// ---------------------------------------------------------------------------
// Kernel 3: SU (1024 x 4096) = s (1024 x 256) @ U (256 x 4096)
// s[r][t] = SE[r*512 + t]; U row-major (t, c*256+u)
// ---------------------------------------------------------------------------
__global__ __launch_bounds__(256)
void k_su(const float* __restrict__ SE, const float* __restrict__ U,
          float* __restrict__ SU)
{
    __shared__ float As[16][68];
    __shared__ float Bs[16][68];
    const int tid = threadIdx.x;
    const int tx = tid & 15, ty = tid >> 4;
    const int bm = blockIdx.x * 64;   // r tile
    const int bn = blockIdx.y * 64;   // (c,u) tile
    float acc[4][4] = {};

    for (int k0 = 0; k0 < T_; k0 += 16) {
#pragma unroll
        for (int i = 0; i < 4; ++i) {
            int idx = tid + i * 256;
            int ar = idx >> 4, ak = idx & 15;
            As[ak][ar] = SE[(bm + ar) * 512 + k0 + ak];
        }
#pragma unroll
        for (int i = 0; i < 4; ++i) {
            int idx = tid + i * 256;
            int bk = idx >> 6, bj = idx & 63;
            Bs[bk][bj] = U[(k0 + bk) * 4096 + bn + bj];
        }
        __syncthreads();
#pragma unroll
        for (int kk = 0; kk < 16; ++kk) {
            float4 a4 = *(const float4*)&As[kk][ty * 4];
            float4 b4 = *(const float4*)&Bs[kk][tx * 4];
            float av[4] = {a4.x, a4.y, a4.z, a4.w};
            float bv[4] = {b4.x, b4.y, b4.z, b4.w};
#pragma unroll
            for (int i = 0; i < 4; ++i)
#pragma unroll
                for (int j = 0; j < 4; ++j)
                    acc[i][j] += av[i] * bv[j];
        }
        __syncthreads();
    }
#pragma unroll
    for (int i = 0; i < 4; ++i) {
        int r = bm + ty * 4 + i;
        float4 o = {acc[i][0], acc[i][1], acc[i][2], acc[i][3]};
        *(float4*)&SU[r * 4096 + bn + tx * 4] = o;
    }
}

// ---------------------------------------------------------------------------
// Kernel 4: per b: OUT[(s,c)][e]^T layout — GEMM M=e(256), N=(s*16+c)(4096),
// K=u(256), NT: A[e][u] = SE[(b*256+e)*512+256+u], B[n][u] = SU[b*2^20+n*256+u]
// Epilogue adds SCEC + WC and writes out[b,s,e,c] (4 contiguous c = float4).
// ---------------------------------------------------------------------------
__global__ __launch_bounds__(256)
void k_pre(const float* __restrict__ SE, const float* __restrict__ SU,
           const float* __restrict__ SCEC, const float* __restrict__ WC,
           float* __restrict__ OUT)
{
    __shared__ float As[16][68];
    __shared__ float Bs[16][68];
    const int tid = threadIdx.x;
    const int tx = tid & 15, ty = tid >> 4;
    const int bm = blockIdx.x * 64;   // e tile (0..192)
    const int bn = blockIdx.y * 64;   // (s,c) tile
    const int b  = blockIdx.z;
    float acc[4][4] = {};

    const float* Abase = SE + (size_t)b * S_ * 512 + 256;  // e rows
    const float* Bbase = SU + (size_t)b * (4096 * 256);

    for (int k0 = 0; k0 < T_; k0 += 16) {
#pragma unroll
        for (int i = 0; i < 4; ++i) {
            int idx = tid + i * 256;
            int ar = idx >> 4, ak = idx & 15;     // ar = e local, ak = u local
            As[ak][ar] = Abase[(bm + ar) * 512 + k0 + ak];
        }
#pragma unroll
        for (int i = 0; i < 4; ++i) {
            int idx = tid + i * 256;
            int bnn = idx >> 4, bk = idx & 15;    // bnn = n local, bk = u local
            Bs[bk][bnn] = Bbase[(bn + bnn) * 256 + k0 + bk];
        }
        __syncthreads();
#pragma unroll
        for (int kk = 0; kk < 16; ++kk) {
            float4 a4 = *(const float4*)&As[kk][ty * 4];
            float4 b4 = *(const float4*)&Bs[kk][tx * 4];
            float av[4] = {a4.x, a4.y, a4.z, a4.w};
            float bv[4] = {b4.x, b4.y, b4.z, b4.w};
#pragma unroll
            for (int i = 0; i < 4; ++i)
#pragma unroll
                for (int j = 0; j < 4; ++j)
                    acc[i][j] += av[i] * bv[j];
        }
        __syncthreads();
    }

    const int n0 = bn + tx * 4;
    const int s  = n0 >> 4;        // global s index
    const int c0 = n0 & 15;        // multiple of 4
    const float4 scv = *(const float4*)&SCEC[(b * S_ + s) * 32 + c0];
#pragma unroll
    for (int i = 0; i < 4; ++i) {
        int e = bm + ty * 4 + i;
        float4 ecv = *(const float4*)&SCEC[(b * S_ + e) * 32 + 16 + c0];
        float4 wcv = *(const float4*)&WC[(s * S_ + e) * 16 + c0];
        float4 o;
        o.x = acc[i][0] + scv.x + ecv.x + wcv.x;
        o.y = acc[i][1] + scv.y + ecv.y + wcv.y;
        o.z = acc[i][2] + scv.z + ecv.z + wcv.z;
        o.w = acc[i][3] + scv.w + ecv.w + wcv.w;
        *(float4*)&OUT[((size_t)(b * S_ + s) * S_ + e) * 16 + c0] = o;
    }
}

// ---------------------------------------------------------------------------
extern "C" void kernel_launch(void* const* d_in, const int* in_sizes, int n_in,
                              void* d_out, int out_size, void* d_ws, size_t ws_size,
                              hipStream_t stream)
{
    const float* fh   = (const float*)d_in[0];  // (4,256,768)
    const float* fv   = (const float*)d_in[1];  // (4,256,32)
    const float* sW   = (const float*)d_in[2];  // (800,256)
    const float* sb   = (const float*)d_in[3];  // (256,)
    const float* eW   = (const float*)d_in[4];  // (800,256)
    const float* eb   = (const float*)d_in[5];  // (256,)
    const float* U    = (const float*)d_in[6];  // (256,16,256)
    const float* WH   = (const float*)d_in[7];  // (256,256,64)
    const float* linW = (const float*)d_in[8];  // (576,16)
    const float* linb = (const float*)d_in[9];  // (16,)
    float* OUT = (float*)d_out;                 // (4,256,256,16)

    float* SE   = (float*)d_ws;              // 1024*512      = 2 MB
    float* SCEC = SE + R_ * 512;             // 1024*32       = 128 KB
    float* WC   = SCEC + R_ * 32;            // 65536*16      = 4 MB
    float* SU   = WC + S_ * S_ * C_;         // 1024*4096     = 16 MB

    k_wc<<<dim3(4096), 256, 0, stream>>>(WH, linW, linb, WC);
    k_se<<<dim3(16, 8), 256, 0, stream>>>(fh, fv, sW, sb, eW, eb, SE);
    k_scec<<<dim3(64), 256, 0, stream>>>(SE, linW, SCEC);
    k_su<<<dim3(16, 64), 256, 0, stream>>>(SE, U, SU);
    k_pre<<<dim3(4, 64, 4), 256, 0, stream>>>(SE, SU, SCEC, WC, OUT);
}

// Round 2
// 81.836 us; speedup vs baseline: 2.4120x; 2.4120x over previous
//
#include <hip/hip_runtime.h>

// BiaffineModule: B=4,S=256,H=768,F=32,T=256,WD=64,C=16
// out[b,s,e,c] = sum_u (sum_t s[b,s,t]U[t,c,u]) e[b,e,u]
//              + (s@Ws)[b,s,c] + (e@We)[b,e,c] + (wh@Ww+lin_b)[s,e,c]

#define B_ 4
#define S_ 256
#define H_ 768
#define F_ 32
#define T_ 256
#define C_ 16
#define R_ (B_*S_)    // 1024
#define HF_ (H_+F_)   // 800

typedef unsigned short u16;
typedef __attribute__((ext_vector_type(8))) short short8;
typedef __attribute__((ext_vector_type(4))) float f32x4;

__device__ __forceinline__ u16 f2b(float x) {
    unsigned u = __builtin_bit_cast(unsigned, x);
    u += 0x7FFF + ((u >> 16) & 1);          // RNE
    return (u16)(u >> 16);
}
__device__ __forceinline__ float b2f(u16 b) {
    unsigned u = ((unsigned)b) << 16;
    return __builtin_bit_cast(float, u);
}

// ---------------------------------------------------------------------------
// Convert x = [fh | fv] -> Xb bf16 [1024][800]
// ---------------------------------------------------------------------------
__global__ __launch_bounds__(256)
void k_cvtx(const float* __restrict__ fh, const float* __restrict__ fv,
            u16* __restrict__ Xb)
{
    int idx = blockIdx.x * 256 + threadIdx.x;   // 204800 chunks of 4
    int r = idx / 200, c4 = idx % 200;
    int k = c4 * 4;
    float4 v = (k < H_) ? *(const float4*)&fh[r * H_ + k]
                        : *(const float4*)&fv[r * F_ + k - H_];
    ushort4 o; o.x = f2b(v.x); o.y = f2b(v.y); o.z = f2b(v.z); o.w = f2b(v.w);
    *(ushort4*)&Xb[idx * 4] = o;
}

// ---------------------------------------------------------------------------
// Wt bf16 [512][800]: Wt[j][k] = (j<256 ? sW : eW)[k][j mod 256]   (transpose)
// ---------------------------------------------------------------------------
__global__ __launch_bounds__(256)
void k_cvtw(const float* __restrict__ sW, const float* __restrict__ eW,
            u16* __restrict__ Wt)
{
    __shared__ float t_[32][33];
    const int k0 = blockIdx.x * 32;   // 25
    const int j0 = blockIdx.y * 32;   // 16
    const int tid = threadIdx.x;
    const float* src = (j0 < T_) ? sW : eW;
    const int js = (j0 < T_) ? j0 : j0 - T_;
    {
        int jl = tid & 31, kl0 = (tid >> 5) * 4;
#pragma unroll
        for (int i = 0; i < 4; ++i)
            t_[kl0 + i][jl] = src[(k0 + kl0 + i) * T_ + js + jl];
    }
    __syncthreads();
    {
        int kl = tid & 31, jl0 = (tid >> 5) * 4;
#pragma unroll
        for (int i = 0; i < 4; ++i)
            Wt[(j0 + jl0 + i) * HF_ + k0 + kl] = f2b(t_[kl][jl0 + i]);
    }
}

// ---------------------------------------------------------------------------
// Ut bf16 [4096][256]: Ut[cu][t] = U[t][cu]   (transpose)
// ---------------------------------------------------------------------------
__global__ __launch_bounds__(256)
void k_cvtu(const float* __restrict__ U, u16* __restrict__ Ut)
{
    __shared__ float t_[32][33];
    const int cu0 = blockIdx.x * 32;  // 128
    const int t0  = blockIdx.y * 32;  // 8
    const int tid = threadIdx.x;
    {
        int cul = tid & 31, tl0 = (tid >> 5) * 4;
#pragma unroll
        for (int i = 0; i < 4; ++i)
            t_[tl0 + i][cul] = U[(t0 + tl0 + i) * 4096 + cu0 + cul];
    }
    __syncthreads();
    {
        int tl = tid & 31, cul0 = (tid >> 5) * 4;
#pragma unroll
        for (int i = 0; i < 4; ++i)
            Ut[(cu0 + cul0 + i) * T_ + t0 + tl] = f2b(t_[tl][cul0 + i]);
    }
}

// ---------------------------------------------------------------------------
// Kernel SE (MFMA): SEb[r][j] bf16 (1024x512) = x @ [sW|eW] + [sb|eb]
// A = Xb [1024][800], Bt = Wt [512][800], K = 800
// ---------------------------------------------------------------------------
__global__ __launch_bounds__(256)
void k_se(const u16* __restrict__ Xb, const u16* __restrict__ Wt,
          const float* __restrict__ sb, const float* __restrict__ eb,
          u16* __restrict__ SEb)
{
    __shared__ u16 Al[64][40];
    __shared__ u16 Bl[64][40];
    const int tid = threadIdx.x;
    const int l = tid & 63, w = tid >> 6;
    const int wr = w >> 1, wc = w & 1;
    const int lr = l & 15, kg = l >> 4;
    const int bm = blockIdx.x * 64, bn = blockIdx.y * 64;
    const int srow = tid >> 2, sc = (tid & 3) * 8;
    f32x4 acc[2][2] = {};

    for (int k0 = 0; k0 < HF_; k0 += 32) {
        uint4 av = *(const uint4*)&Xb[(bm + srow) * HF_ + k0 + sc];
        uint4 bv = *(const uint4*)&Wt[(bn + srow) * HF_ + k0 + sc];
        __syncthreads();
        *(uint4*)&Al[srow][sc] = av;
        *(uint4*)&Bl[srow][sc] = bv;
        __syncthreads();
        short8 a0 = *(const short8*)&Al[wr * 32 + lr][kg * 8];
        short8 a1 = *(const short8*)&Al[wr * 32 + 16 + lr][kg * 8];
        short8 b0 = *(const short8*)&Bl[wc * 32 + lr][kg * 8];
        short8 b1 = *(const short8*)&Bl[wc * 32 + 16 + lr][kg * 8];
        acc[0][0] = __builtin_amdgcn_mfma_f32_16x16x32_bf16(a0, b0, acc[0][0], 0, 0, 0);
        acc[0][1] = __builtin_amdgcn_mfma_f32_16x16x32_bf16(a0, b1, acc[0][1], 0, 0, 0);
        acc[1][0] = __builtin_amdgcn_mfma_f32_16x16x32_bf16(a1, b0, acc[1][0], 0, 0, 0);
        acc[1][1] = __builtin_amdgcn_mfma_f32_16x16x32_bf16(a1, b1, acc[1][1], 0, 0, 0);
    }
#pragma unroll
    for (int j = 0; j < 2; ++j) {
        int col = bn + wc * 32 + j * 16 + lr;
        float bias = (col < T_) ? sb[col] : eb[col - T_];
#pragma unroll
        for (int i = 0; i < 2; ++i)
#pragma unroll
            for (int q = 0; q < 4; ++q) {
                int r = bm + wr * 32 + i * 16 + kg * 4 + q;
                SEb[r * 512 + col] = f2b(acc[i][j][q] + bias);
            }
    }
}

// ---------------------------------------------------------------------------
// Kernel SCEC: SCEC[r][0:16] = s@Ws, [16:32] = e@We  (f32, from bf16 SEb)
// ---------------------------------------------------------------------------
__global__ __launch_bounds__(256)
void k_scec(const u16* __restrict__ SEb, const float* __restrict__ linW,
            float* __restrict__ SCEC)
{
    __shared__ float SEl[16][512];
    const int tid = threadIdx.x;
    const int r0 = blockIdx.x * 16;
#pragma unroll
    for (int i = 0; i < 8; ++i) {
        int ch = tid + i * 256;
        int rl = ch >> 7, o4 = (ch & 127) * 4;
        ushort4 v = *(const ushort4*)&SEb[(r0 + rl) * 512 + o4];
        SEl[rl][o4 + 0] = b2f(v.x); SEl[rl][o4 + 1] = b2f(v.y);
        SEl[rl][o4 + 2] = b2f(v.z); SEl[rl][o4 + 3] = b2f(v.w);
    }
    __syncthreads();
    const int rl = tid >> 4, c = tid & 15;
    float accs = 0.f, acce = 0.f;
#pragma unroll 4
    for (int t = 0; t < 256; ++t) {
        accs += SEl[rl][t]       * linW[t * 16 + c];
        acce += SEl[rl][256 + t] * linW[(256 + t) * 16 + c];
    }
    SCEC[(r0 + rl) * 32 + c]      = accs;
    SCEC[(r0 + rl) * 32 + 16 + c] = acce;
}

// ---------------------------------------------------------------------------
// Kernel WC: WC[se][c] = width_hidden[se][:] @ Ww + lin_b[c]   (f32)
// ---------------------------------------------------------------------------
__global__ __launch_bounds__(256)
void k_wc(const float* __restrict__ WH, const float* __restrict__ linW,
          const float* __restrict__ linb, float* __restrict__ WC)
{
    __shared__ float Wl[16][64];
    __shared__ float Wwl[64][16];
    const int tid = threadIdx.x;
    const int se0 = blockIdx.x * 16;
    {
        int sel = tid >> 4, w4 = tid & 15;
        *(float4*)&Wl[sel][w4 * 4] = *(const float4*)&WH[(se0 + sel) * 64 + w4 * 4];
    }
    {
        int w = tid >> 2, c4 = tid & 3;
        *(float4*)&Wwl[w][c4 * 4] = *(const float4*)&linW[(512 + w) * 16 + c4 * 4];
    }
    __syncthreads();
    const int sel = tid >> 4, c = tid & 15;
    float acc = linb[c];
#pragma unroll
    for (int w = 0; w < 64; ++w)
        acc += Wl[sel][w] * Wwl[w][c];
    WC[(se0 + sel) * 16 + c] = acc;
}

// ---------------------------------------------------------------------------
// Kernel SU (MFMA): SUb[r][cu] bf16 (1024 x 4096) = s @ U
// A = SEb[r][0:256] (stride 512), Bt = Ut [4096][256], K=256
// ---------------------------------------------------------------------------
__global__ __launch_bounds__(256)
void k_su(const u16* __restrict__ SEb, const u16* __restrict__ Ut,
          u16* __restrict__ SUb)
{
    __shared__ u16 Al[64][40];
    __shared__ u16 Bl[64][40];
    const int tid = threadIdx.x;
    const int l = tid & 63, w = tid >> 6;
    const int wr = w >> 1, wc = w & 1;
    const int lr = l & 15, kg = l >> 4;
    const int bm = blockIdx.x * 64, bn = blockIdx.y * 64;
    const int srow = tid >> 2, sc = (tid & 3) * 8;
    f32x4 acc[2][2] = {};

    for (int k0 = 0; k0 < T_; k0 += 32) {
        uint4 av = *(const uint4*)&SEb[(bm + srow) * 512 + k0 + sc];
        uint4 bv = *(const uint4*)&Ut[(bn + srow) * T_ + k0 + sc];
        __syncthreads();
        *(uint4*)&Al[srow][sc] = av;
        *(uint4*)&Bl[srow][sc] = bv;
        __syncthreads();
        short8 a0 = *(const short8*)&Al[wr * 32 + lr][kg * 8];
        short8 a1 = *(const short8*)&Al[wr * 32 + 16 + lr][kg * 8];
        short8 b0 = *(const short8*)&Bl[wc * 32 + lr][kg * 8];
        short8 b1 = *(const short8*)&Bl[wc * 32 + 16 + lr][kg * 8];
        acc[0][0] = __builtin_amdgcn_mfma_f32_16x16x32_bf16(a0, b0, acc[0][0], 0, 0, 0);
        acc[0][1] = __builtin_amdgcn_mfma_f32_16x16x32_bf16(a0, b1, acc[0][1], 0, 0, 0);
        acc[1][0] = __builtin_amdgcn_mfma_f32_16x16x32_bf16(a1, b0, acc[1][0], 0, 0, 0);
        acc[1][1] = __builtin_amdgcn_mfma_f32_16x16x32_bf16(a1, b1, acc[1][1], 0, 0, 0);
    }
#pragma unroll
    for (int i = 0; i < 2; ++i)
#pragma unroll
        for (int j = 0; j < 2; ++j)
#pragma unroll
            for (int q = 0; q < 4; ++q) {
                int r  = bm + wr * 32 + i * 16 + kg * 4 + q;
                int cc = bn + wc * 32 + j * 16 + lr;
                SUb[r * 4096 + cc] = f2b(acc[i][j][q]);
            }
}

// ---------------------------------------------------------------------------
// Kernel PRE (MFMA): per b, M=e(256), N=(s,c)(4096), K=u(256)
// A = SEb[(b,e)][256:512], Bt = SUb[b][(s,c)][u]; epilogue adds SCEC+WC -> OUT
// ---------------------------------------------------------------------------
__global__ __launch_bounds__(256)
void k_pre(const u16* __restrict__ SEb, const u16* __restrict__ SUb,
           const float* __restrict__ SCEC, const float* __restrict__ WC,
           float* __restrict__ OUT)
{
    __shared__ u16 Al[64][40];
    __shared__ u16 Bl[64][40];
    const int tid = threadIdx.x;
    const int l = tid & 63, w = tid >> 6;
    const int wr = w >> 1, wc = w & 1;
    const int lr = l & 15, kg = l >> 4;
    const int bm = blockIdx.x * 64, bn = blockIdx.y * 64;
    const int b  = blockIdx.z;
    const int srow = tid >> 2, sc = (tid & 3) * 8;
    f32x4 acc[2][2] = {};

    const u16* Abase = SEb + (b << 8) * 512 + 256;
    const u16* Bbase = SUb + ((size_t)b << 20);

    for (int k0 = 0; k0 < T_; k0 += 32) {
        uint4 av = *(const uint4*)&Abase[(bm + srow) * 512 + k0 + sc];
        uint4 bv = *(const uint4*)&Bbase[(bn + srow) * T_ + k0 + sc];
        __syncthreads();
        *(uint4*)&Al[srow][sc] = av;
        *(uint4*)&Bl[srow][sc] = bv;
        __syncthreads();
        short8 a0 = *(const short8*)&Al[wr * 32 + lr][kg * 8];
        short8 a1 = *(const short8*)&Al[wr * 32 + 16 + lr][kg * 8];
        short8 b0 = *(const short8*)&Bl[wc * 32 + lr][kg * 8];
        short8 b1 = *(const short8*)&Bl[wc * 32 + 16 + lr][kg * 8];
        acc[0][0] = __builtin_amdgcn_mfma_f32_16x16x32_bf16(a0, b0, acc[0][0], 0, 0, 0);
        acc[0][1] = __builtin_amdgcn_mfma_f32_16x16x32_bf16(a0, b1, acc[0][1], 0, 0, 0);
        acc[1][0] = __builtin_amdgcn_mfma_f32_16x16x32_bf16(a1, b0, acc[1][0], 0, 0, 0);
        acc[1][1] = __builtin_amdgcn_mfma_f32_16x16x32_bf16(a1, b1, acc[1][1], 0, 0, 0);
    }

#pragma unroll
    for (int j = 0; j < 2; ++j) {
        int n = bn + wc * 32 + j * 16 + lr;
        int s = n >> 4, c = n & 15;
        float scv = SCEC[((b << 8) + s) * 32 + c];
#pragma unroll
        for (int i = 0; i < 2; ++i)
#pragma unroll
            for (int q = 0; q < 4; ++q) {
                int e = bm + wr * 32 + i * 16 + kg * 4 + q;
                float ecv = SCEC[((b << 8) + e) * 32 + 16 + c];
                float wcv = WC[(s * S_ + e) * 16 + c];
                OUT[(((size_t)(b << 8) + s) * S_ + e) * 16 + c] =
                    acc[i][j][q] + scv + ecv + wcv;
            }
    }
}

// ---------------------------------------------------------------------------
extern "C" void kernel_launch(void* const* d_in, const int* in_sizes, int n_in,
                              void* d_out, int out_size, void* d_ws, size_t ws_size,
                              hipStream_t stream)
{
    const float* fh   = (const float*)d_in[0];
    const float* fv   = (const float*)d_in[1];
    const float* sW   = (const float*)d_in[2];
    const float* sb   = (const float*)d_in[3];
    const float* eW   = (const float*)d_in[4];
    const float* eb   = (const float*)d_in[5];
    const float* U    = (const float*)d_in[6];
    const float* WH   = (const float*)d_in[7];
    const float* linW = (const float*)d_in[8];
    const float* linb = (const float*)d_in[9];
    float* OUT = (float*)d_out;

    char* p = (char*)d_ws;
    u16* SEb = (u16*)p;            p += (size_t)R_ * 512 * 2;       // 1 MB
    u16* SUb = (u16*)p;            p += (size_t)B_ * 4096 * 256 * 2; // 8 MB
    u16* Xb  = (u16*)p;            p += (size_t)R_ * HF_ * 2;       // 1.6 MB
    u16* Wt  = (u16*)p;            p += (size_t)512 * HF_ * 2;      // 0.8 MB
    u16* Ut  = (u16*)p;            p += (size_t)4096 * T_ * 2;      // 2 MB
    float* SCEC = (float*)p;       p += (size_t)R_ * 32 * 4;        // 128 KB
    float* WC   = (float*)p;       p += (size_t)S_ * S_ * C_ * 4;   // 4 MB

    k_cvtx<<<dim3(800), 256, 0, stream>>>(fh, fv, Xb);
    k_cvtw<<<dim3(25, 16), 256, 0, stream>>>(sW, eW, Wt);
    k_cvtu<<<dim3(128, 8), 256, 0, stream>>>(U, Ut);
    k_wc<<<dim3(4096), 256, 0, stream>>>(WH, linW, linb, WC);
    k_se<<<dim3(16, 8), 256, 0, stream>>>(Xb, Wt, sb, eb, SEb);
    k_scec<<<dim3(64), 256, 0, stream>>>(SEb, linW, SCEC);
    k_su<<<dim3(16, 64), 256, 0, stream>>>(SEb, Ut, SUb);
    k_pre<<<dim3(4, 64, 4), 256, 0, stream>>>(SEb, SUb, SCEC, WC, OUT);
}

// Round 3
// 74.536 us; speedup vs baseline: 2.6482x; 1.0979x over previous
//
#include <hip/hip_runtime.h>

// BiaffineModule: B=4,S=256,H=768,F=32,T=256,WD=64,C=16
// out[b,s,e,c] = sum_u (sum_t s[b,s,t]U[t,c,u]) e[b,e,u]
//              + (s@Ws)[b,s,c] + (e@We)[b,e,c] + (wh@Ww+lin_b)[s,e,c]

#define B_ 4
#define S_ 256
#define H_ 768
#define F_ 32
#define T_ 256
#define C_ 16
#define R_ 1024
#define HF 800
#define HFP 832   // K padded to multiple of 64

typedef unsigned short u16;
typedef __attribute__((ext_vector_type(8))) short short8;
typedef __attribute__((ext_vector_type(4))) float f32x4;

__device__ __forceinline__ u16 f2b(float x) {
    unsigned u = __builtin_bit_cast(unsigned, x);
    u += 0x7FFF + ((u >> 16) & 1);          // RNE
    return (u16)(u >> 16);
}
__device__ __forceinline__ float b2f(u16 b) {
    unsigned u = ((unsigned)b) << 16;
    return __builtin_bit_cast(float, u);
}

// ---------------------------------------------------------------------------
// k_prep: all conversions + WC, one launch, blockIdx-ranged jobs.
//  job0 [0,832):     Xb bf16 [1024][832] = [fh|fv|0pad]
//  job1 [832,1232):  Wt bf16 [512][832]  = [sW|eW]^T (transpose, no pad cols)
//  job2 [1232,1248): Wt pad cols 800..831 = 0
//  job3 [1248,2272): Ut bf16 [4096][256] = U^T
//  job4 [2272,6368): WC f32 [65536][16] = WH @ Ww + lin_b
// ---------------------------------------------------------------------------
__global__ __launch_bounds__(256)
void k_prep(const float* __restrict__ fh, const float* __restrict__ fv,
            const float* __restrict__ sW, const float* __restrict__ eW,
            const float* __restrict__ U,  const float* __restrict__ WH,
            const float* __restrict__ linW, const float* __restrict__ linb,
            u16* __restrict__ Xb, u16* __restrict__ Wt, u16* __restrict__ Ut,
            float* __restrict__ WC)
{
    const int bid = blockIdx.x;
    const int tid = threadIdx.x;

    if (bid < 832) {                               // --- cvtx + pad
        int idx = bid * 256 + tid;                 // 1024 rows x 208 chunks
        int r = idx / 208, c4 = idx % 208;
        int k = c4 * 4;
        float4 v;
        if (k < H_)       v = *(const float4*)&fh[r * H_ + k];
        else if (k < HF)  v = *(const float4*)&fv[r * F_ + k - H_];
        else              v = make_float4(0.f, 0.f, 0.f, 0.f);
        ushort4 o; o.x = f2b(v.x); o.y = f2b(v.y); o.z = f2b(v.z); o.w = f2b(v.w);
        *(ushort4*)&Xb[(size_t)r * HFP + k] = o;
        return;
    }
    if (bid < 1232) {                              // --- cvtw (transpose)
        __shared__ float t_[32][33];
        int bid2 = bid - 832;
        int k0 = (bid2 / 16) * 32;                 // 0..768
        int j0 = (bid2 % 16) * 32;
        const float* src = (j0 < T_) ? sW : eW;
        const int js = (j0 < T_) ? j0 : j0 - T_;
        {
            int jl = tid & 31, kl0 = (tid >> 5) * 4;
#pragma unroll
            for (int i = 0; i < 4; ++i)
                t_[kl0 + i][jl] = src[(k0 + kl0 + i) * T_ + js + jl];
        }
        __syncthreads();
        {
            int kl = tid & 31, jl0 = (tid >> 5) * 4;
#pragma unroll
            for (int i = 0; i < 4; ++i)
                Wt[(size_t)(j0 + jl0 + i) * HFP + k0 + kl] = f2b(t_[kl][jl0 + i]);
        }
        return;
    }
    if (bid < 1248) {                              // --- Wt pad
        int idx = (bid - 1232) * 256 + tid;        // 512 rows x 8 chunks
        int r = idx >> 3, c4 = idx & 7;
        ushort4 z; z.x = z.y = z.z = z.w = 0;
        *(ushort4*)&Wt[(size_t)r * HFP + HF + c4 * 4] = z;
        return;
    }
    if (bid < 2272) {                              // --- cvtu (transpose)
        __shared__ float t_[32][33];
        int bid2 = bid - 1248;
        int cu0 = (bid2 >> 3) * 32;                // 0..4064
        int t0  = (bid2 & 7) * 32;
        {
            int cul = tid & 31, tl0 = (tid >> 5) * 4;
#pragma unroll
            for (int i = 0; i < 4; ++i)
                t_[tl0 + i][cul] = U[(size_t)(t0 + tl0 + i) * 4096 + cu0 + cul];
        }
        __syncthreads();
        {
            int tl = tid & 31, cul0 = (tid >> 5) * 4;
#pragma unroll
            for (int i = 0; i < 4; ++i)
                Ut[(size_t)(cu0 + cul0 + i) * T_ + t0 + tl] = f2b(t_[tl][cul0 + i]);
        }
        return;
    }
    {                                              // --- wc
        __shared__ float Wl[16][64];
        __shared__ float Wwl[64][16];
        int se0 = (bid - 2272) * 16;
        {
            int sel = tid >> 4, w4 = tid & 15;
            *(float4*)&Wl[sel][w4 * 4] = *(const float4*)&WH[(size_t)(se0 + sel) * 64 + w4 * 4];
        }
        {
            int w = tid >> 2, c4 = tid & 3;
            *(float4*)&Wwl[w][c4 * 4] = *(const float4*)&linW[(512 + w) * 16 + c4 * 4];
        }
        __syncthreads();
        int sel = tid >> 4, c = tid & 15;
        float acc = linb[c];
#pragma unroll
        for (int w = 0; w < 64; ++w)
            acc += Wl[sel][w] * Wwl[w][c];
        WC[(size_t)(se0 + sel) * 16 + c] = acc;
    }
}

// ---------------------------------------------------------------------------
// LDS-free NT GEMM core: both A[M][K] and Bt[N][K] fragments are contiguous
// 8xbf16 K-slices -> direct global_load_dwordx4 per lane, no barriers.
// Wave (wr,wc) owns a 32x32 output quadrant (2x2 16x16x32 MFMA frags).
// ---------------------------------------------------------------------------
template<int K>
__device__ __forceinline__ void gemm_core(const u16* __restrict__ Ag, int lda,
                                          const u16* __restrict__ Bg, int ldb,
                                          int wr, int wc, int lr, int kgl,
                                          f32x4 acc[2][2])
{
    const u16* ar0 = Ag + (size_t)(wr * 32 + lr) * lda + kgl * 8;
    const u16* ar1 = ar0 + 16 * (size_t)lda;
    const u16* br0 = Bg + (size_t)(wc * 32 + lr) * ldb + kgl * 8;
    const u16* br1 = br0 + 16 * (size_t)ldb;
#pragma unroll 4
    for (int k = 0; k < K; k += 32) {
        short8 a0 = *(const short8*)(ar0 + k);
        short8 a1 = *(const short8*)(ar1 + k);
        short8 b0 = *(const short8*)(br0 + k);
        short8 b1 = *(const short8*)(br1 + k);
        acc[0][0] = __builtin_amdgcn_mfma_f32_16x16x32_bf16(a0, b0, acc[0][0], 0, 0, 0);
        acc[0][1] = __builtin_amdgcn_mfma_f32_16x16x32_bf16(a0, b1, acc[0][1], 0, 0, 0);
        acc[1][0] = __builtin_amdgcn_mfma_f32_16x16x32_bf16(a1, b0, acc[1][0], 0, 0, 0);
        acc[1][1] = __builtin_amdgcn_mfma_f32_16x16x32_bf16(a1, b1, acc[1][1], 0, 0, 0);
    }
}

// ---------------------------------------------------------------------------
// k_se: SEb[1024][512] = x @ [sW|eW] + [sb|eb]   (A=Xb, Bt=Wt, K=832)
// ---------------------------------------------------------------------------
__global__ __launch_bounds__(256)
void k_se(const u16* __restrict__ Xb, const u16* __restrict__ Wt,
          const float* __restrict__ sb, const float* __restrict__ eb,
          u16* __restrict__ SEb)
{
    const int tid = threadIdx.x;
    const int l = tid & 63, w = tid >> 6;
    const int wr = w >> 1, wc = w & 1;
    const int lr = l & 15, kgl = l >> 4;
    const int bm = blockIdx.x * 64, bn = blockIdx.y * 64;
    f32x4 acc[2][2] = {};

    gemm_core<HFP>(Xb + (size_t)bm * HFP, HFP, Wt + (size_t)bn * HFP, HFP,
                   wr, wc, lr, kgl, acc);

#pragma unroll
    for (int j = 0; j < 2; ++j) {
        int col = bn + wc * 32 + j * 16 + lr;
        float bias = (col < T_) ? sb[col] : eb[col - T_];
#pragma unroll
        for (int i = 0; i < 2; ++i)
#pragma unroll
            for (int q = 0; q < 4; ++q) {
                int r = bm + wr * 32 + i * 16 + kgl * 4 + q;
                SEb[(size_t)r * 512 + col] = f2b(acc[i][j][q] + bias);
            }
    }
}

// ---------------------------------------------------------------------------
// k_scec: SCEC[r][0:16] = s@Ws, [16:32] = e@We  (256 blocks x 4 rows)
// ---------------------------------------------------------------------------
__global__ __launch_bounds__(256)
void k_scec(const u16* __restrict__ SEb, const float* __restrict__ linW,
            float* __restrict__ SCEC)
{
    __shared__ float SEl[4][512];
    const int tid = threadIdx.x;
    const int r0 = blockIdx.x * 4;
#pragma unroll
    for (int i = 0; i < 2; ++i) {
        int ch = tid + i * 256;                    // 0..511
        int rl = ch >> 7, o4 = (ch & 127) * 4;
        ushort4 v = *(const ushort4*)&SEb[(size_t)(r0 + rl) * 512 + o4];
        SEl[rl][o4 + 0] = b2f(v.x); SEl[rl][o4 + 1] = b2f(v.y);
        SEl[rl][o4 + 2] = b2f(v.z); SEl[rl][o4 + 3] = b2f(v.w);
    }
    __syncthreads();
    const int rl = tid >> 6, tq = (tid >> 4) & 3, c = tid & 15;
    const int t0 = tq * 64;
    float accs = 0.f, acce = 0.f;
#pragma unroll 4
    for (int t = t0; t < t0 + 64; ++t) {
        accs += SEl[rl][t]       * linW[t * 16 + c];
        acce += SEl[rl][256 + t] * linW[(256 + t) * 16 + c];
    }
    accs += __shfl_xor(accs, 16); accs += __shfl_xor(accs, 32);
    acce += __shfl_xor(acce, 16); acce += __shfl_xor(acce, 32);
    if (tq == 0) {
        SCEC[(r0 + rl) * 32 + c]      = accs;
        SCEC[(r0 + rl) * 32 + 16 + c] = acce;
    }
}

// ---------------------------------------------------------------------------
// k_su: SUb[1024][4096] bf16 = s @ U   (A=SEb[:, 0:256] lda=512, Bt=Ut, K=256)
// ---------------------------------------------------------------------------
__global__ __launch_bounds__(256)
void k_su(const u16* __restrict__ SEb, const u16* __restrict__ Ut,
          u16* __restrict__ SUb)
{
    const int tid = threadIdx.x;
    const int l = tid & 63, w = tid >> 6;
    const int wr = w >> 1, wc = w & 1;
    const int lr = l & 15, kgl = l >> 4;
    const int bm = blockIdx.x * 64, bn = blockIdx.y * 64;
    f32x4 acc[2][2] = {};

    gemm_core<T_>(SEb + (size_t)bm * 512, 512, Ut + (size_t)bn * T_, T_,
                  wr, wc, lr, kgl, acc);

#pragma unroll
    for (int i = 0; i < 2; ++i)
#pragma unroll
        for (int j = 0; j < 2; ++j)
#pragma unroll
            for (int q = 0; q < 4; ++q) {
                int r  = bm + wr * 32 + i * 16 + kgl * 4 + q;
                int cc = bn + wc * 32 + j * 16 + lr;
                SUb[(size_t)r * 4096 + cc] = f2b(acc[i][j][q]);
            }
}

// ---------------------------------------------------------------------------
// k_pre: per b, M=e(256), N=(s,c)(4096), K=u(256)
// A = SEb[b rows][256:512] lda=512, Bt = SUb[b]; epilogue adds SCEC+WC -> OUT
// ---------------------------------------------------------------------------
__global__ __launch_bounds__(256)
void k_pre(const u16* __restrict__ SEb, const u16* __restrict__ SUb,
           const float* __restrict__ SCEC, const float* __restrict__ WC,
           float* __restrict__ OUT)
{
    const int tid = threadIdx.x;
    const int l = tid & 63, w = tid >> 6;
    const int wr = w >> 1, wc = w & 1;
    const int lr = l & 15, kgl = l >> 4;
    const int bm = blockIdx.x * 64, bn = blockIdx.y * 64;
    const int b  = blockIdx.z;
    f32x4 acc[2][2] = {};

    const u16* Abase = SEb + (size_t)(b << 8) * 512 + 256 + (size_t)bm * 512;
    const u16* Bbase = SUb + ((size_t)b << 20) + (size_t)bn * T_;

    gemm_core<T_>(Abase, 512, Bbase, T_, wr, wc, lr, kgl, acc);

#pragma unroll
    for (int j = 0; j < 2; ++j) {
        int n = bn + wc * 32 + j * 16 + lr;
        int s = n >> 4, c = n & 15;
        float scv = SCEC[((b << 8) + s) * 32 + c];
#pragma unroll
        for (int i = 0; i < 2; ++i)
#pragma unroll
            for (int q = 0; q < 4; ++q) {
                int e = bm + wr * 32 + i * 16 + kgl * 4 + q;
                float ecv = SCEC[((b << 8) + e) * 32 + 16 + c];
                float wcv = WC[(size_t)(s * S_ + e) * 16 + c];
                OUT[(((size_t)(b << 8) + s) * S_ + e) * 16 + c] =
                    acc[i][j][q] + scv + ecv + wcv;
            }
    }
}

// ---------------------------------------------------------------------------
extern "C" void kernel_launch(void* const* d_in, const int* in_sizes, int n_in,
                              void* d_out, int out_size, void* d_ws, size_t ws_size,
                              hipStream_t stream)
{
    const float* fh   = (const float*)d_in[0];
    const float* fv   = (const float*)d_in[1];
    const float* sW   = (const float*)d_in[2];
    const float* sb   = (const float*)d_in[3];
    const float* eW   = (const float*)d_in[4];
    const float* eb   = (const float*)d_in[5];
    const float* U    = (const float*)d_in[6];
    const float* WH   = (const float*)d_in[7];
    const float* linW = (const float*)d_in[8];
    const float* linb = (const float*)d_in[9];
    float* OUT = (float*)d_out;

    char* p = (char*)d_ws;
    u16* SUb = (u16*)p;      p += (size_t)B_ * 4096 * 256 * 2;   // 8 MB
    float* WC = (float*)p;   p += (size_t)S_ * S_ * C_ * 4;      // 4 MB
    u16* Ut  = (u16*)p;      p += (size_t)4096 * T_ * 2;         // 2 MB
    u16* Xb  = (u16*)p;      p += (size_t)R_ * HFP * 2;          // 1.7 MB
    u16* Wt  = (u16*)p;      p += (size_t)512 * HFP * 2;         // 0.85 MB
    u16* SEb = (u16*)p;      p += (size_t)R_ * 512 * 2;          // 1 MB
    float* SCEC = (float*)p; p += (size_t)R_ * 32 * 4;           // 128 KB

    k_prep<<<dim3(6368), 256, 0, stream>>>(fh, fv, sW, eW, U, WH, linW, linb,
                                           Xb, Wt, Ut, WC);
    k_se  <<<dim3(16, 8), 256, 0, stream>>>(Xb, Wt, sb, eb, SEb);
    k_scec<<<dim3(256), 256, 0, stream>>>(SEb, linW, SCEC);
    k_su  <<<dim3(16, 64), 256, 0, stream>>>(SEb, Ut, SUb);
    k_pre <<<dim3(4, 64, 4), 256, 0, stream>>>(SEb, SUb, SCEC, WC, OUT);
}

// Round 4
// 61.184 us; speedup vs baseline: 3.2262x; 1.2182x over previous
//
#include <hip/hip_runtime.h>

// BiaffineModule: B=4,S=256,H=768,F=32,T=256,WD=64,C=16
// out[b,s,e,c] = sum_u (sum_t s[b,s,t]U[t,c,u]) e[b,e,u]
//              + (s@Ws)[b,s,c] + (e@We)[b,e,c] + (wh@Ww+lin_b)[s,e,c]

#define B_ 4
#define S_ 256
#define H_ 768
#define F_ 32
#define T_ 256
#define C_ 16
#define R_ 1024
#define HF 800
#define HFP 832   // K padded to multiple of 64

typedef unsigned short u16;
typedef __attribute__((ext_vector_type(8))) short short8;
typedef __attribute__((ext_vector_type(4))) float f32x4;

__device__ __forceinline__ u16 f2b(float x) {
    unsigned u = __builtin_bit_cast(unsigned, x);
    u += 0x7FFF + ((u >> 16) & 1);          // RNE
    return (u16)(u >> 16);
}
__device__ __forceinline__ float b2f(u16 b) {
    unsigned u = ((unsigned)b) << 16;
    return __builtin_bit_cast(float, u);
}

// ---------------------------------------------------------------------------
// k_prep: all conversions + WC, one launch, blockIdx-ranged jobs.
// ---------------------------------------------------------------------------
__global__ __launch_bounds__(256)
void k_prep(const float* __restrict__ fh, const float* __restrict__ fv,
            const float* __restrict__ sW, const float* __restrict__ eW,
            const float* __restrict__ U,  const float* __restrict__ WH,
            const float* __restrict__ linW, const float* __restrict__ linb,
            u16* __restrict__ Xb, u16* __restrict__ Wt, u16* __restrict__ Ut,
            float* __restrict__ WC)
{
    const int bid = blockIdx.x;
    const int tid = threadIdx.x;

    if (bid < 832) {                               // --- cvtx + pad
        int idx = bid * 256 + tid;                 // 1024 rows x 208 chunks
        int r = idx / 208, c4 = idx % 208;
        int k = c4 * 4;
        float4 v;
        if (k < H_)       v = *(const float4*)&fh[r * H_ + k];
        else if (k < HF)  v = *(const float4*)&fv[r * F_ + k - H_];
        else              v = make_float4(0.f, 0.f, 0.f, 0.f);
        ushort4 o; o.x = f2b(v.x); o.y = f2b(v.y); o.z = f2b(v.z); o.w = f2b(v.w);
        *(ushort4*)&Xb[(size_t)r * HFP + k] = o;
        return;
    }
    if (bid < 1232) {                              // --- cvtw (transpose)
        __shared__ float t_[32][33];
        int bid2 = bid - 832;
        int k0 = (bid2 / 16) * 32;                 // 0..768
        int j0 = (bid2 % 16) * 32;
        const float* src = (j0 < T_) ? sW : eW;
        const int js = (j0 < T_) ? j0 : j0 - T_;
        {
            int jl = tid & 31, kl0 = (tid >> 5) * 4;
#pragma unroll
            for (int i = 0; i < 4; ++i)
                t_[kl0 + i][jl] = src[(k0 + kl0 + i) * T_ + js + jl];
        }
        __syncthreads();
        {
            int kl = tid & 31, jl0 = (tid >> 5) * 4;
#pragma unroll
            for (int i = 0; i < 4; ++i)
                Wt[(size_t)(j0 + jl0 + i) * HFP + k0 + kl] = f2b(t_[kl][jl0 + i]);
        }
        return;
    }
    if (bid < 1248) {                              // --- Wt pad
        int idx = (bid - 1232) * 256 + tid;        // 512 rows x 8 chunks
        int r = idx >> 3, c4 = idx & 7;
        ushort4 z; z.x = z.y = z.z = z.w = 0;
        *(ushort4*)&Wt[(size_t)r * HFP + HF + c4 * 4] = z;
        return;
    }
    if (bid < 2272) {                              // --- cvtu (transpose)
        __shared__ float t_[32][33];
        int bid2 = bid - 1248;
        int cu0 = (bid2 >> 3) * 32;                // 0..4064
        int t0  = (bid2 & 7) * 32;
        {
            int cul = tid & 31, tl0 = (tid >> 5) * 4;
#pragma unroll
            for (int i = 0; i < 4; ++i)
                t_[tl0 + i][cul] = U[(size_t)(t0 + tl0 + i) * 4096 + cu0 + cul];
        }
        __syncthreads();
        {
            int tl = tid & 31, cul0 = (tid >> 5) * 4;
#pragma unroll
            for (int i = 0; i < 4; ++i)
                Ut[(size_t)(cu0 + cul0 + i) * T_ + t0 + tl] = f2b(t_[tl][cul0 + i]);
        }
        return;
    }
    {                                              // --- wc
        __shared__ float Wl[16][64];
        __shared__ float Wwl[64][16];
        int se0 = (bid - 2272) * 16;
        {
            int sel = tid >> 4, w4 = tid & 15;
            *(float4*)&Wl[sel][w4 * 4] = *(const float4*)&WH[(size_t)(se0 + sel) * 64 + w4 * 4];
        }
        {
            int w = tid >> 2, c4 = tid & 3;
            *(float4*)&Wwl[w][c4 * 4] = *(const float4*)&linW[(512 + w) * 16 + c4 * 4];
        }
        __syncthreads();
        int sel = tid >> 4, c = tid & 15;
        float acc = linb[c];
#pragma unroll
        for (int w = 0; w < 64; ++w)
            acc += Wl[sel][w] * Wwl[w][c];
        WC[(size_t)(se0 + sel) * 16 + c] = acc;
    }
}

// ---------------------------------------------------------------------------
// LDS-free NT GEMM core, MFxNF 16x16 fragments per wave.
// A = M-operand rows (output rows, vectorized dim), B = N-operand rows.
// A/B pre-offset to this wave's m_base/n_base row.
// ---------------------------------------------------------------------------
template<int K, int LDA, int LDB, int MF, int NF, int UNROLL>
__device__ __forceinline__ void core(const u16* __restrict__ A,
                                     const u16* __restrict__ B,
                                     int lr, int kgl, f32x4 acc[MF][NF])
{
    const u16* ap[MF];
    const u16* bp[NF];
#pragma unroll
    for (int i = 0; i < MF; ++i) ap[i] = A + (size_t)(i * 16 + lr) * LDA + kgl * 8;
#pragma unroll
    for (int j = 0; j < NF; ++j) bp[j] = B + (size_t)(j * 16 + lr) * LDB + kgl * 8;

#pragma unroll UNROLL
    for (int k = 0; k < K; k += 32) {
        short8 a[MF], b[NF];
#pragma unroll
        for (int i = 0; i < MF; ++i) a[i] = *(const short8*)(ap[i] + k);
#pragma unroll
        for (int j = 0; j < NF; ++j) b[j] = *(const short8*)(bp[j] + k);
#pragma unroll
        for (int i = 0; i < MF; ++i)
#pragma unroll
            for (int j = 0; j < NF; ++j)
                acc[i][j] = __builtin_amdgcn_mfma_f32_16x16x32_bf16(a[i], b[j], acc[i][j], 0, 0, 0);
    }
}

// ---------------------------------------------------------------------------
// k_se: SEb[1024][512] = x @ [sW|eW] + [sb|eb]
// M-operand = Wt rows (j), N-operand = Xb rows (r). Tile 64j x 64r, 2x2 waves.
// ---------------------------------------------------------------------------
__global__ __launch_bounds__(256)
void k_se(const u16* __restrict__ Xb, const u16* __restrict__ Wt,
          const float* __restrict__ sb, const float* __restrict__ eb,
          u16* __restrict__ SEb)
{
    const int tid = threadIdx.x;
    const int l = tid & 63, w = tid >> 6;
    const int wr = w >> 1, wc = w & 1;
    const int lr = l & 15, kgl = l >> 4;
    const int bm = blockIdx.x * 64;   // j
    const int bn = blockIdx.y * 64;   // r
    f32x4 acc[2][2] = {};

    core<HFP, HFP, HFP, 2, 2, 2>(Wt + (size_t)(bm + wr * 32) * HFP,
                                 Xb + (size_t)(bn + wc * 32) * HFP,
                                 lr, kgl, acc);

#pragma unroll
    for (int i = 0; i < 2; ++i) {
        int j0 = bm + wr * 32 + i * 16 + kgl * 4;     // 4 consecutive j
        float4 bias = (j0 < T_) ? *(const float4*)&sb[j0]
                                : *(const float4*)&eb[j0 - T_];
#pragma unroll
        for (int jj = 0; jj < 2; ++jj) {
            int r = bn + wc * 32 + jj * 16 + lr;
            ushort4 o;
            o.x = f2b(acc[i][jj][0] + bias.x);
            o.y = f2b(acc[i][jj][1] + bias.y);
            o.z = f2b(acc[i][jj][2] + bias.z);
            o.w = f2b(acc[i][jj][3] + bias.w);
            *(ushort4*)&SEb[(size_t)r * 512 + j0] = o;
        }
    }
}

// ---------------------------------------------------------------------------
// k_su_scec: fused launch.
//  blocks [0,256):   SUb[r][cu] = s @ U   (M-op = Ut rows cu, N-op = SEb rows r)
//                    tile 128cu x 128r, 4 waves each 64x64 (4x4 frags)
//  blocks [256,512): SCEC[r][0:16]=s@Ws, [16:32]=e@We
// ---------------------------------------------------------------------------
__global__ __launch_bounds__(256)
void k_su_scec(const u16* __restrict__ SEb, const u16* __restrict__ Ut,
               const float* __restrict__ linW,
               u16* __restrict__ SUb, float* __restrict__ SCEC)
{
    const int bid = blockIdx.x;
    const int tid = threadIdx.x;

    if (bid < 256) {
        const int l = tid & 63, w = tid >> 6;
        const int wr = w >> 1, wc = w & 1;
        const int lr = l & 15, kgl = l >> 4;
        const int bm = (bid & 31) * 128;   // cu
        const int bn = (bid >> 5) * 128;   // r
        f32x4 acc[4][4] = {};

        core<T_, T_, 512, 4, 4, 2>(Ut + (size_t)(bm + wr * 64) * T_,
                                   SEb + (size_t)(bn + wc * 64) * 512,
                                   lr, kgl, acc);

#pragma unroll
        for (int i = 0; i < 4; ++i) {
            int cu0 = bm + wr * 64 + i * 16 + kgl * 4;
#pragma unroll
            for (int j = 0; j < 4; ++j) {
                int r = bn + wc * 64 + j * 16 + lr;
                ushort4 o;
                o.x = f2b(acc[i][j][0]); o.y = f2b(acc[i][j][1]);
                o.z = f2b(acc[i][j][2]); o.w = f2b(acc[i][j][3]);
                *(ushort4*)&SUb[(size_t)r * 4096 + cu0] = o;
            }
        }
        return;
    }

    // ---- SCEC ----
    __shared__ float SEl[4][512];
    const int r0 = (bid - 256) * 4;
#pragma unroll
    for (int i = 0; i < 2; ++i) {
        int ch = tid + i * 256;                    // 0..511
        int rl = ch >> 7, o4 = (ch & 127) * 4;
        ushort4 v = *(const ushort4*)&SEb[(size_t)(r0 + rl) * 512 + o4];
        SEl[rl][o4 + 0] = b2f(v.x); SEl[rl][o4 + 1] = b2f(v.y);
        SEl[rl][o4 + 2] = b2f(v.z); SEl[rl][o4 + 3] = b2f(v.w);
    }
    __syncthreads();
    const int rl = tid >> 6, tq = (tid >> 4) & 3, c = tid & 15;
    const int t0 = tq * 64;
    float accs = 0.f, acce = 0.f;
#pragma unroll 4
    for (int t = t0; t < t0 + 64; ++t) {
        accs += SEl[rl][t]       * linW[t * 16 + c];
        acce += SEl[rl][256 + t] * linW[(256 + t) * 16 + c];
    }
    accs += __shfl_xor(accs, 16); accs += __shfl_xor(accs, 32);
    acce += __shfl_xor(acce, 16); acce += __shfl_xor(acce, 32);
    if (tq == 0) {
        SCEC[(r0 + rl) * 32 + c]      = accs;
        SCEC[(r0 + rl) * 32 + 16 + c] = acce;
    }
}

// ---------------------------------------------------------------------------
// k_pre: per b: M-op = SUb rows n=(s,c), N-op = SEb e-rows. K=u(256).
// Tile 128n x 128e, 4 waves each 64x64 (4x4 frags). float4 epilogue.
// ---------------------------------------------------------------------------
__global__ __launch_bounds__(256)
void k_pre(const u16* __restrict__ SEb, const u16* __restrict__ SUb,
           const float* __restrict__ SCEC, const float* __restrict__ WC,
           float* __restrict__ OUT)
{
    const int tid = threadIdx.x;
    const int l = tid & 63, w = tid >> 6;
    const int wr = w >> 1, wc = w & 1;
    const int lr = l & 15, kgl = l >> 4;
    const int bm = blockIdx.x * 128;   // n = (s,c)
    const int bn = blockIdx.y * 128;   // e
    const int b  = blockIdx.z;
    f32x4 acc[4][4] = {};

    const u16* An = SUb + ((size_t)b << 20) + (size_t)(bm + wr * 64) * T_;
    const u16* Be = SEb + (size_t)(b << 8) * 512 + 256 + (size_t)(bn + wc * 64) * 512;

    core<T_, T_, 512, 4, 4, 2>(An, Be, lr, kgl, acc);

    const int c0 = kgl * 4;
    float4 scv[4];
#pragma unroll
    for (int i = 0; i < 4; ++i) {
        int s = (bm + wr * 64 + i * 16) >> 4;      // kgl*4 < 16, same s
        scv[i] = *(const float4*)&SCEC[((b << 8) + s) * 32 + c0];
    }
#pragma unroll
    for (int j = 0; j < 4; ++j) {
        int e = bn + wc * 64 + j * 16 + lr;
        float4 ecv = *(const float4*)&SCEC[((b << 8) + e) * 32 + 16 + c0];
#pragma unroll
        for (int i = 0; i < 4; ++i) {
            int s = (bm + wr * 64 + i * 16) >> 4;
            float4 wcv = *(const float4*)&WC[(size_t)(s * S_ + e) * 16 + c0];
            float4 o;
            o.x = acc[i][j][0] + scv[i].x + ecv.x + wcv.x;
            o.y = acc[i][j][1] + scv[i].y + ecv.y + wcv.y;
            o.z = acc[i][j][2] + scv[i].z + ecv.z + wcv.z;
            o.w = acc[i][j][3] + scv[i].w + ecv.w + wcv.w;
            *(float4*)&OUT[(((size_t)(b << 8) + s) * S_ + e) * 16 + c0] = o;
        }
    }
}

// ---------------------------------------------------------------------------
extern "C" void kernel_launch(void* const* d_in, const int* in_sizes, int n_in,
                              void* d_out, int out_size, void* d_ws, size_t ws_size,
                              hipStream_t stream)
{
    const float* fh   = (const float*)d_in[0];
    const float* fv   = (const float*)d_in[1];
    const float* sW   = (const float*)d_in[2];
    const float* sb   = (const float*)d_in[3];
    const float* eW   = (const float*)d_in[4];
    const float* eb   = (const float*)d_in[5];
    const float* U    = (const float*)d_in[6];
    const float* WH   = (const float*)d_in[7];
    const float* linW = (const float*)d_in[8];
    const float* linb = (const float*)d_in[9];
    float* OUT = (float*)d_out;

    char* p = (char*)d_ws;
    u16* SUb = (u16*)p;      p += (size_t)B_ * 4096 * 256 * 2;   // 8 MB
    float* WC = (float*)p;   p += (size_t)S_ * S_ * C_ * 4;      // 4 MB
    u16* Ut  = (u16*)p;      p += (size_t)4096 * T_ * 2;         // 2 MB
    u16* Xb  = (u16*)p;      p += (size_t)R_ * HFP * 2;          // 1.7 MB
    u16* Wt  = (u16*)p;      p += (size_t)512 * HFP * 2;         // 0.85 MB
    u16* SEb = (u16*)p;      p += (size_t)R_ * 512 * 2;          // 1 MB
    float* SCEC = (float*)p; p += (size_t)R_ * 32 * 4;           // 128 KB

    k_prep<<<dim3(6368), 256, 0, stream>>>(fh, fv, sW, eW, U, WH, linW, linb,
                                           Xb, Wt, Ut, WC);
    k_se  <<<dim3(8, 16), 256, 0, stream>>>(Xb, Wt, sb, eb, SEb);
    k_su_scec<<<dim3(512), 256, 0, stream>>>(SEb, Ut, linW, SUb, SCEC);
    k_pre <<<dim3(32, 2, 4), 256, 0, stream>>>(SEb, SUb, SCEC, WC, OUT);
}